// Round 1
// baseline (247.403 us; speedup 1.0000x reference)
//
#include <hip/hip_runtime.h>
#include <math.h>

// Problem dims (fixed by setup_inputs)
#define B_N 256
#define C_N 1152
#define I_N 8
#define N_N 10
#define D_N 16

constexpr int C_CHUNKS = 48;            // parallelism over the c-reduction
constexpr int C_PER    = C_N / C_CHUNKS; // 24
constexpr int KC       = 4;             // c's staged per LDS round
constexpr int ROUNDS   = C_PER / KC;    // 6
constexpr int B_TILE   = 16;            // batch elements per block
constexpr int SLOTS    = 16;            // lanes per batch element (10 active n's)
constexpr int BLOCK    = B_TILE * SLOTS; // 256
constexpr int WS_STRIDE = 132;          // 128 + 4 pad -> <=2-way LDS bank conflict (free)
constexpr int WS_PER_C  = N_N * WS_STRIDE; // 1320
constexpr int XS_STRIDE = C_PER * I_N + 4; // 196 (pad: b-groups land on different banks)

// ws layout: vsum [B,N,D] floats, then p_s [C_CHUNKS][B][N][D] floats (total ~8.03 MB)

// One routing pass: recompute u_hat[b,:,c,:] from W,x; logits from vsum; softmax over n;
// accumulate partial s over this block's c-range.  FIRST=true: coef = 1/N (softmax of 0),
// vsum not read (ws is poison-initialized, so pass 0 must not read it).
template <bool FIRST>
__global__ __launch_bounds__(BLOCK)
void route_pass(const float* __restrict__ x, const float* __restrict__ W,
                const float* __restrict__ vsum, float* __restrict__ p_s)
{
    __shared__ float xs[B_TILE * XS_STRIDE];   // x[b_tile, c_range, :]
    __shared__ float Ws[KC * WS_PER_C];        // W[:, c0:c0+KC, :, :] transposed-padded

    const int tid     = threadIdx.x;
    const int b_local = tid >> 4;
    const int slot    = tid & 15;
    const bool active = (slot < N_N);
    const int  n      = active ? slot : (N_N - 1);   // clamp idle lanes (broadcast, free)
    const int  chunk  = blockIdx.x;
    const int  gb0    = blockIdx.y * B_TILE;
    const int  gb     = gb0 + b_local;
    const int  cbase  = chunk * C_PER;

    // ---- stage x tile once (coalesced float4) ----
    {
        const float4* x4 = reinterpret_cast<const float4*>(x);
        for (int f = tid; f < (B_TILE * C_PER * I_N) / 4; f += BLOCK) {
            const int e   = f * 4;
            const int bl  = e / (C_PER * I_N);
            const int off = e - bl * (C_PER * I_N);
            float4 v = x4[(size_t)(gb0 + bl) * (C_N * I_N / 4) + (size_t)cbase * 2 + (off >> 2)];
            *reinterpret_cast<float4*>(&xs[bl * XS_STRIDE + off]) = v;
        }
    }

    // ---- vsum fragment in registers ----
    float vs[D_N];
    if (!FIRST) {
        const float* vp = vsum + ((size_t)gb * N_N + n) * D_N;
        #pragma unroll
        for (int d = 0; d < D_N; d += 4) {
            float4 v = *reinterpret_cast<const float4*>(vp + d);
            vs[d] = v.x; vs[d + 1] = v.y; vs[d + 2] = v.z; vs[d + 3] = v.w;
        }
    }

    float s_acc[D_N];
    #pragma unroll
    for (int d = 0; d < D_N; ++d) s_acc[d] = 0.f;

    const float4* W4 = reinterpret_cast<const float4*>(W);

    for (int round = 0; round < ROUNDS; ++round) {
        __syncthreads();
        // ---- stage W for KC c's: 5120 floats, coalesced float4 ----
        const int c0 = cbase + round * KC;
        for (int f = tid; f < (KC * N_N * 128) / 4; f += BLOCK) {
            const int e  = f * 4;
            const int cc = e / (N_N * 128);
            const int r  = e - cc * (N_N * 128);
            const int nn = r >> 7;
            const int k  = r & 127;
            float4 v = W4[(size_t)nn * (C_N * 128 / 4) + (size_t)(c0 + cc) * 32 + (k >> 2)];
            *reinterpret_cast<float4*>(&Ws[cc * WS_PER_C + nn * WS_STRIDE + k]) = v;
        }
        __syncthreads();

        #pragma unroll
        for (int cc = 0; cc < KC; ++cc) {
            const int crel = round * KC + cc;
            const float* xp = &xs[b_local * XS_STRIDE + crel * I_N];
            const float4 xa = *reinterpret_cast<const float4*>(xp);
            const float4 xb = *reinterpret_cast<const float4*>(xp + 4);
            const float* wp = &Ws[cc * WS_PER_C + n * WS_STRIDE];

            float u[D_N];
            #pragma unroll
            for (int d = 0; d < D_N; ++d) {
                const float4 wa = *reinterpret_cast<const float4*>(wp + d * 8);
                const float4 wb = *reinterpret_cast<const float4*>(wp + d * 8 + 4);
                u[d] = wa.x * xa.x + wa.y * xa.y + wa.z * xa.z + wa.w * xa.w
                     + wb.x * xb.x + wb.y * xb.y + wb.z * xb.z + wb.w * xb.w;
            }

            float coef;
            if (FIRST) {
                coef = 1.0f / (float)N_N;
            } else {
                float logit = 0.f;
                #pragma unroll
                for (int d = 0; d < D_N; ++d) logit += u[d] * vs[d];
                if (!active) logit = -1e30f;
                float m = logit;
                #pragma unroll
                for (int off = 1; off < 16; off <<= 1) m = fmaxf(m, __shfl_xor(m, off, 64));
                const float e1 = active ? __expf(logit - m) : 0.f;
                float Z = e1;
                #pragma unroll
                for (int off = 1; off < 16; off <<= 1) Z += __shfl_xor(Z, off, 64);
                coef = e1 / Z;
            }
            #pragma unroll
            for (int d = 0; d < D_N; ++d) s_acc[d] += coef * u[d];
        }
    }

    if (active) {
        float* outp = &p_s[(((size_t)chunk * B_N + gb) * N_N + n) * D_N];
        #pragma unroll
        for (int d = 0; d < D_N; d += 4) {
            float4 v = make_float4(s_acc[d], s_acc[d + 1], s_acc[d + 2], s_acc[d + 3]);
            *reinterpret_cast<float4*>(outp + d) = v;
        }
    }
}

// Sum partials over chunks, squash, then: phase0 vsum=v; phase1 vsum+=v; phase2 out=v.
__global__ __launch_bounds__(BLOCK)
void reduce_squash(const float* __restrict__ p_s, float* __restrict__ vsum,
                   float* __restrict__ out, int phase)
{
    const int tid = threadIdx.x;
    const int lg  = tid >> 4;
    const int d   = tid & 15;
    const int gg  = blockIdx.x * 16 + lg;   // 0..2559 == b*10+n

    float s = 0.f;
    for (int cc = 0; cc < C_CHUNKS; ++cc)
        s += p_s[((size_t)cc * (B_N * N_N) + gg) * D_N + d];

    float sq = s * s;
    #pragma unroll
    for (int off = 1; off < 16; off <<= 1) sq += __shfl_xor(sq, off, 64);

    const float scale = (sq / (1.f + sq)) / (sqrtf(sq) + 1e-8f);
    const float v = scale * s;

    if (phase == 0)      vsum[(size_t)gg * D_N + d] = v;
    else if (phase == 1) vsum[(size_t)gg * D_N + d] += v;
    else                 out[(size_t)gg * D_N + d] = v;
}

extern "C" void kernel_launch(void* const* d_in, const int* in_sizes, int n_in,
                              void* d_out, int out_size, void* d_ws, size_t ws_size,
                              hipStream_t stream)
{
    const float* x = (const float*)d_in[0];
    const float* W = (const float*)d_in[1];
    float* out  = (float*)d_out;
    float* vsum = (float*)d_ws;                         // B*N*D floats
    float* p_s  = vsum + (size_t)B_N * N_N * D_N;       // C_CHUNKS*B*N*D floats

    dim3 grid(C_CHUNKS, B_N / B_TILE);
    dim3 blk(BLOCK);
    dim3 rgrid((B_N * N_N) / 16);

    // pass 0: coef = 1/N (softmax of zero logits) -> v0
    route_pass<true><<<grid, blk, 0, stream>>>(x, W, nullptr, p_s);
    reduce_squash<<<rgrid, blk, 0, stream>>>(p_s, vsum, out, 0);
    // pass 1: logits = dot(u_hat, v0) -> v1, vsum = v0+v1
    route_pass<false><<<grid, blk, 0, stream>>>(x, W, vsum, p_s);
    reduce_squash<<<rgrid, blk, 0, stream>>>(p_s, vsum, out, 1);
    // pass 2: logits = dot(u_hat, v0+v1) -> output v2
    route_pass<false><<<grid, blk, 0, stream>>>(x, W, vsum, p_s);
    reduce_squash<<<rgrid, blk, 0, stream>>>(p_s, vsum, out, 2);
}